// Round 9
// baseline (1637.649 us; speedup 1.0000x reference)
//
#include <hip/hip_runtime.h>
#include <hip/hip_bf16.h>

// ContentAgree: B=4, DIM=256, N=16384, K=64, H=4, HD=64, FF=512
// Device dtypes (evidence r6/r8): INPUTS f32, OUTPUT f32.
// Intermediates bf16 (ws 110.1 MB proven available), compute f32.
//   region0: xs_bf (NEL bf16) -> fo_bf ; region1: q_bf -> oa_bf
//   region0+1: h_bf (2*NEL bf16) after LN1 ; region2: v_bf -> ffnin_bf
//   region3: small f32 ; d_out (f32, 67MB): scores_bf -> f2_bf -> final f32 output

#define NB 4
#define DIM 256
#define NN 16384
#define KK 64
#define HH 4
#define HD 64
#define FF 512
#define MTOT (NB * NN)           // 65536 rows
#define BH (NB * HH)             // 16

typedef unsigned short bf16u;

__device__ __forceinline__ float b2f(bf16u u) {
    return __uint_as_float(((unsigned)u) << 16);
}
__device__ __forceinline__ bf16u f2b(float f) {
    unsigned x = __float_as_uint(f);
    unsigned r = (x + 0x7fffu + ((x >> 16) & 1u)) >> 16;
    return (bf16u)r;
}
__device__ __forceinline__ float wave_max(float v) {
#pragma unroll
    for (int off = 32; off > 0; off >>= 1) v = fmaxf(v, __shfl_xor(v, off));
    return v;
}
__device__ __forceinline__ float wave_sum(float v) {
#pragma unroll
    for (int off = 32; off > 0; off >>= 1) v += __shfl_xor(v, off);
    return v;
}

// ---------------------------------------------------------------- transpose in
// x: (B, DIM, N) f32 -> xs: (B, N, DIM) bf16
__global__ __launch_bounds__(256) void k_transpose_in(const float* __restrict__ x,
                                                      bf16u* __restrict__ xs) {
    __shared__ float tile[32][33];
    int b = blockIdx.z;
    int n0 = blockIdx.x * 32, c0 = blockIdx.y * 32;
    int tx = threadIdx.x, ty = threadIdx.y;
#pragma unroll
    for (int i = 0; i < 32; i += 8)
        tile[ty + i][tx] = x[((size_t)b * DIM + c0 + ty + i) * NN + n0 + tx];
    __syncthreads();
#pragma unroll
    for (int i = 0; i < 32; i += 8)
        xs[((size_t)b * NN + n0 + ty + i) * DIM + c0 + tx] = f2b(tile[tx][ty + i]);
}

// ---------------------------------------------------------------- K1 = C@Wq+bq
// C: (B, K, DIM) f32, Wq: (DIM, DIM) f32 -> K1f: (B*K, DIM) f32
__global__ __launch_bounds__(256) void k_proj_small(const float* __restrict__ C,
                                                    const float* __restrict__ Wq,
                                                    const float* __restrict__ bq,
                                                    float* __restrict__ K1f) {
    __shared__ float crow[DIM];
    int bk = blockIdx.x;  // 0..255 = b*64+k
    int t = threadIdx.x;
    crow[t] = C[(size_t)bk * DIM + t];
    __syncthreads();
    float acc = bq[t];
    for (int d = 0; d < DIM; ++d) acc += crow[d] * Wq[d * DIM + t];
    K1f[(size_t)bk * DIM + t] = acc;
}

// ---------------------------------------------------------------- attn2
__global__ __launch_bounds__(256) void k_attn2(const float* __restrict__ K1f,
                                               float* __restrict__ attn2f) {
    __shared__ float k1s[64][65];
    __shared__ float sbuf[64][65];
    int bh = blockIdx.x;
    int b = bh >> 2, h = bh & 3;
    int t = threadIdx.x;
#pragma unroll
    for (int i = 0; i < 16; ++i) {
        int idx = t + i * 256;
        int k = idx >> 6, hd = idx & 63;
        k1s[k][hd] = K1f[((size_t)b * KK + k) * DIM + h * HD + hd];
    }
    __syncthreads();
    int k = t >> 2, j0 = (t & 3) * 16;
    for (int jj = 0; jj < 16; ++jj) {
        int j = j0 + jj;
        float acc = 0.f;
#pragma unroll
        for (int d = 0; d < 64; ++d) acc += k1s[k][d] * k1s[j][d];
        sbuf[k][j] = acc * 0.125f;
    }
    __syncthreads();
    int lane = t & 63, w = t >> 6;
    for (int r = w; r < 64; r += 4) {
        float v = sbuf[r][lane];
        float m = wave_max(v);
        float p = expf(v - m);
        float s = wave_sum(p);
        attn2f[((size_t)bh * KK + r) * KK + lane] = p / s;
    }
}

// ---------------------------------------------------------------- tiled GEMM
// C(M,Nc) = A(M,Kd)[bf16] @ Bw(Kd,Nc)[f32] + bias[f32] ; EPI: 0 none, 1 gelu, 2 +Res[bf16]
template <int EPI>
__global__ __launch_bounds__(256) void gemm_bf(const bf16u* __restrict__ A,
                                               const float* __restrict__ Bw,
                                               const float* __restrict__ bias,
                                               const bf16u* __restrict__ Res,
                                               bf16u* __restrict__ Cout,
                                               int M, int Kd, int Nc) {
    __shared__ float As[32][65];
    __shared__ float Bs[32][65];
    int t = threadIdx.x;
    int m0 = blockIdx.x * 64, n0 = blockIdx.y * 64;
    int tx = t & 15, ty = t >> 4;
    int r0 = ty * 4, c0 = tx * 4;
    float acc[4][4] = {};
    int ar = t >> 2;            // 0..63
    int ak = (t & 3) * 8;       // 0,8,16,24
    int bk = t >> 3;            // 0..31
    int bn = (t & 7) * 8;       // 0..56
    const bf16u* aptr = A + (size_t)(m0 + ar) * Kd + ak;
    const float* bptr = Bw + (size_t)bk * Nc + n0 + bn;
    for (int k0 = 0; k0 < Kd; k0 += 32) {
        int4 av = *reinterpret_cast<const int4*>(aptr);
        float4 bv0 = *reinterpret_cast<const float4*>(bptr);
        float4 bv1 = *reinterpret_cast<const float4*>(bptr + 4);
        As[ak + 0][ar] = b2f((bf16u)(av.x & 0xffff));
        As[ak + 1][ar] = b2f((bf16u)((unsigned)av.x >> 16));
        As[ak + 2][ar] = b2f((bf16u)(av.y & 0xffff));
        As[ak + 3][ar] = b2f((bf16u)((unsigned)av.y >> 16));
        As[ak + 4][ar] = b2f((bf16u)(av.z & 0xffff));
        As[ak + 5][ar] = b2f((bf16u)((unsigned)av.z >> 16));
        As[ak + 6][ar] = b2f((bf16u)(av.w & 0xffff));
        As[ak + 7][ar] = b2f((bf16u)((unsigned)av.w >> 16));
        Bs[bk][bn + 0] = bv0.x; Bs[bk][bn + 1] = bv0.y;
        Bs[bk][bn + 2] = bv0.z; Bs[bk][bn + 3] = bv0.w;
        Bs[bk][bn + 4] = bv1.x; Bs[bk][bn + 5] = bv1.y;
        Bs[bk][bn + 6] = bv1.z; Bs[bk][bn + 7] = bv1.w;
        __syncthreads();
#pragma unroll
        for (int kk = 0; kk < 32; ++kk) {
            float avv[4], bvv[4];
#pragma unroll
            for (int i = 0; i < 4; ++i) avv[i] = As[kk][r0 + i];
#pragma unroll
            for (int j = 0; j < 4; ++j) bvv[j] = Bs[kk][c0 + j];
#pragma unroll
            for (int i = 0; i < 4; ++i)
#pragma unroll
                for (int j = 0; j < 4; ++j) acc[i][j] += avv[i] * bvv[j];
        }
        __syncthreads();
        aptr += 32;
        bptr += (size_t)32 * Nc;
    }
#pragma unroll
    for (int i = 0; i < 4; ++i) {
        int row = m0 + r0 + i;
#pragma unroll
        for (int j = 0; j < 4; ++j) {
            int col = n0 + c0 + j;
            float v = acc[i][j] + bias[col];
            if (EPI == 1) v = 0.5f * v * (1.0f + erff(v * 0.7071067811865476f));
            if (EPI == 2) v += b2f(Res[(size_t)row * Nc + col]);
            Cout[(size_t)row * Nc + col] = f2b(v);
        }
    }
}

// ---------------------------------------------------------------- scores
// scores[bh,n,k] = scale * Q[b,n,h*64+:]·K1h[k,:]  (bf16 out, in d_out)
__global__ __launch_bounds__(256) void k_scores(const bf16u* __restrict__ Qbuf,
                                                const float* __restrict__ K1f,
                                                bf16u* __restrict__ scores) {
    __shared__ float k1t[64][65];  // [hd][k]
    __shared__ float qrow[4][64];
    int bh = blockIdx.x;
    int b = bh >> 2, h = bh & 3;
    int n0 = blockIdx.y * 128;
    int t = threadIdx.x;
#pragma unroll
    for (int i = 0; i < 16; ++i) {
        int idx = t + i * 256;
        int k = idx >> 6, hd = idx & 63;
        k1t[hd][k] = K1f[((size_t)b * KK + k) * DIM + h * HD + hd];
    }
    __syncthreads();
    int w = t >> 6, lane = t & 63;
    for (int it = 0; it < 32; ++it) {
        int n = n0 + it * 4 + w;
        qrow[w][lane] = b2f(Qbuf[((size_t)b * NN + n) * DIM + h * HD + lane]);
        __syncthreads();
        float acc = 0.f;
#pragma unroll
        for (int d = 0; d < 64; ++d) acc += qrow[w][d] * k1t[d][lane];
        scores[((size_t)bh * NN + n) * KK + lane] = f2b(acc * 0.125f);
        __syncthreads();
    }
}

// ---------------------------------------------------------------- col max (chunked)
__global__ __launch_bounds__(256) void k_cmax(const bf16u* __restrict__ scores,
                                              float* __restrict__ cmaxpart) {
    int bh = blockIdx.x, ch = blockIdx.y;
    int t = threadIdx.x, w = t >> 6, lane = t & 63;
    int n0 = ch * 512;
    float m = -1e30f;
    for (int i = 0; i < 128; ++i) {
        int n = n0 + i * 4 + w;
        m = fmaxf(m, b2f(scores[((size_t)bh * NN + n) * KK + lane]));
    }
    __shared__ float red[4][64];
    red[w][lane] = m;
    __syncthreads();
    if (w == 0) {
        m = fmaxf(fmaxf(red[0][lane], red[1][lane]), fmaxf(red[2][lane], red[3][lane]));
        cmaxpart[((size_t)bh * 32 + ch) * 64 + lane] = m;
    }
}

__global__ void k_colmax(const float* __restrict__ cmaxpart, float* __restrict__ colmax) {
    int bh = blockIdx.x, lane = threadIdx.x;  // 64 threads
    float m = -1e30f;
    for (int ch = 0; ch < 32; ++ch)
        m = fmaxf(m, cmaxpart[((size_t)bh * 32 + ch) * 64 + lane]);
    colmax[bh * 64 + lane] = m;
}

// ---------------------------------------------------------------- w2 partials
__global__ __launch_bounds__(256) void k_w2(const bf16u* __restrict__ scores,
                                            const bf16u* __restrict__ Vbuf,
                                            const float* __restrict__ colmax,
                                            float* __restrict__ w2part,
                                            float* __restrict__ psumpart) {
    int bh = blockIdx.x, ch = blockIdx.y;
    int b = bh >> 2, h = bh & 3;
    int t = threadIdx.x, w = t >> 6, lane = t & 63;
    float mk = colmax[bh * 64 + lane];
    float acc[16] = {};
    float psum = 0.f;
    __shared__ float prow[4][64], vrow[4][64];
    int n0 = ch * 512;
    for (int i = 0; i < 128; ++i) {
        int n = n0 + i * 4 + w;
        float p = expf(b2f(scores[((size_t)bh * NN + n) * KK + lane]) - mk);
        psum += p;
        prow[w][lane] = p;
        vrow[w][lane] = b2f(Vbuf[((size_t)b * NN + n) * DIM + h * HD + lane]);
        __syncthreads();
#pragma unroll
        for (int r = 0; r < 4; ++r) {
            float v = vrow[r][lane];
#pragma unroll
            for (int j = 0; j < 16; ++j) acc[j] += prow[r][w + 4 * j] * v;
        }
        __syncthreads();
    }
#pragma unroll
    for (int j = 0; j < 16; ++j) {
        int k = w + 4 * j;
        w2part[(((size_t)bh * 32 + ch) * 64 + k) * 64 + lane] = acc[j];
    }
    __shared__ float pred[4][64];
    pred[w][lane] = psum;
    __syncthreads();
    if (t < 64) {
        float s = pred[0][t] + pred[1][t] + pred[2][t] + pred[3][t];
        psumpart[((size_t)bh * 32 + ch) * 64 + t] = s;
    }
}

__global__ __launch_bounds__(256) void k_w2fin(const float* __restrict__ w2part,
                                               const float* __restrict__ psumpart,
                                               float* __restrict__ w2f) {
    int bh = blockIdx.x, t = threadIdx.x;
    __shared__ float stot[64];
    if (t < 64) {
        float s = 0.f;
        for (int ch = 0; ch < 32; ++ch) s += psumpart[((size_t)bh * 32 + ch) * 64 + t];
        stot[t] = s;
    }
    __syncthreads();
#pragma unroll
    for (int i = 0; i < 16; ++i) {
        int idx = t + i * 256;
        int k = idx >> 6, hd = idx & 63;
        float s = 0.f;
        for (int ch = 0; ch < 32; ++ch)
            s += w2part[(((size_t)bh * 32 + ch) * 64 + k) * 64 + hd];
        w2f[(size_t)bh * 4096 + idx] = s / stot[k];
    }
}

// ---------------------------------------------------------------- fused row out
__global__ __launch_bounds__(256) void k_out(const bf16u* __restrict__ scores,
                                             const float* __restrict__ attn2f,
                                             const float* __restrict__ w2f,
                                             bf16u* __restrict__ out_attn) {
    __shared__ float a2[64][65];
    __shared__ float w2[64][65];
    __shared__ float arow[4][64];
    __shared__ float w1row[4][64];
    int bh = blockIdx.x;
    int b = bh >> 2, h = bh & 3;
    int n0 = blockIdx.y * 128;
    int t = threadIdx.x, w = t >> 6, lane = t & 63;
#pragma unroll
    for (int i = 0; i < 16; ++i) {
        int idx = t + i * 256;
        int k = idx >> 6, j = idx & 63;
        a2[k][j] = attn2f[(size_t)bh * 4096 + idx];
        w2[k][j] = w2f[(size_t)bh * 4096 + idx];
    }
    __syncthreads();
    for (int it = 0; it < 32; ++it) {
        int n = n0 + it * 4 + w;
        float s = b2f(scores[((size_t)bh * NN + n) * KK + lane]);
        float m = wave_max(s);
        float p = expf(s - m);
        float sum = wave_sum(p);
        arow[w][lane] = p / sum;
        __syncthreads();
        float acc = 0.f;
#pragma unroll
        for (int k = 0; k < 64; ++k) acc += arow[w][k] * a2[k][lane];
        w1row[w][lane] = acc;
        __syncthreads();
        float o = 0.f;
#pragma unroll
        for (int k = 0; k < 64; ++k) o += w1row[w][k] * w2[k][lane];
        out_attn[((size_t)b * NN + n) * DIM + lane * 4 + h] = f2b(o);
        __syncthreads();
    }
}

// ---------------------------------------------------------------- LN kernels (g, b f32)
__global__ __launch_bounds__(256) void k_ln1(const bf16u* __restrict__ oa,
                                             const bf16u* __restrict__ xs,
                                             const float* __restrict__ g,
                                             const float* __restrict__ bb,
                                             bf16u* __restrict__ ffn_in) {
    int m = blockIdx.x * 4 + (threadIdx.x >> 6);
    int lane = threadIdx.x & 63;
    ushort4 a = reinterpret_cast<const ushort4*>(oa + (size_t)m * DIM)[lane];
    ushort4 x = reinterpret_cast<const ushort4*>(xs + (size_t)m * DIM)[lane];
    float v[4] = {b2f(a.x) + b2f(x.x), b2f(a.y) + b2f(x.y),
                  b2f(a.z) + b2f(x.z), b2f(a.w) + b2f(x.w)};
    float s = wave_sum(v[0] + v[1] + v[2] + v[3]);
    float mean = s * (1.0f / 256.0f);
    float q = 0.f;
#pragma unroll
    for (int i = 0; i < 4; ++i) { float d = v[i] - mean; q += d * d; }
    q = wave_sum(q);
    float inv = rsqrtf(q * (1.0f / 256.0f) + 1e-5f);
    ushort4 o;
    bf16u* po = &o.x;
#pragma unroll
    for (int i = 0; i < 4; ++i) {
        int c = lane * 4 + i;
        po[i] = f2b((v[i] - mean) * inv * g[c] + bb[c]);
    }
    reinterpret_cast<ushort4*>(ffn_in + (size_t)m * DIM)[lane] = o;
}

__global__ __launch_bounds__(256) void k_ln2(const bf16u* __restrict__ f2,
                                             const float* __restrict__ g,
                                             const float* __restrict__ bb,
                                             bf16u* __restrict__ fo) {
    int m = blockIdx.x * 4 + (threadIdx.x >> 6);
    int lane = threadIdx.x & 63;
    ushort4 a = reinterpret_cast<const ushort4*>(f2 + (size_t)m * DIM)[lane];
    float v[4] = {b2f(a.x), b2f(a.y), b2f(a.z), b2f(a.w)};
    float s = wave_sum(v[0] + v[1] + v[2] + v[3]);
    float mean = s * (1.0f / 256.0f);
    float q = 0.f;
#pragma unroll
    for (int i = 0; i < 4; ++i) { float d = v[i] - mean; q += d * d; }
    q = wave_sum(q);
    float inv = rsqrtf(q * (1.0f / 256.0f) + 1e-5f);
    ushort4 o;
    bf16u* po = &o.x;
#pragma unroll
    for (int i = 0; i < 4; ++i) {
        int c = lane * 4 + i;
        po[i] = f2b((v[i] - mean) * inv * g[c] + bb[c]);
    }
    reinterpret_cast<ushort4*>(fo + (size_t)m * DIM)[lane] = o;
}

// ---------------------------------------------------------------- transpose out
// fo: (B,N,DIM) bf16 -> out: (B,DIM,N) f32
__global__ __launch_bounds__(256) void k_transpose_out(const bf16u* __restrict__ fo,
                                                       float* __restrict__ out) {
    __shared__ bf16u tile[32][34];
    int b = blockIdx.z;
    int n0 = blockIdx.x * 32, c0 = blockIdx.y * 32;
    int tx = threadIdx.x, ty = threadIdx.y;
#pragma unroll
    for (int i = 0; i < 32; i += 8)
        tile[ty + i][tx] = fo[((size_t)b * NN + n0 + ty + i) * DIM + c0 + tx];
    __syncthreads();
#pragma unroll
    for (int i = 0; i < 32; i += 8)
        out[((size_t)b * DIM + c0 + ty + i) * NN + n0 + tx] = b2f(tile[tx][ty + i]);
}

// ---------------------------------------------------------------- launch
extern "C" void kernel_launch(void* const* d_in, const int* in_sizes, int n_in,
                              void* d_out, int out_size, void* d_ws, size_t ws_size,
                              hipStream_t stream) {
    const float* x   = (const float*)d_in[0];
    const float* C   = (const float*)d_in[1];
    // d_in[2] = G (unused by reference)
    const float* Wq  = (const float*)d_in[3];
    const float* bq  = (const float*)d_in[4];
    const float* Wk  = (const float*)d_in[5];
    const float* bk  = (const float*)d_in[6];
    const float* Wv  = (const float*)d_in[7];
    const float* bv  = (const float*)d_in[8];
    const float* W1  = (const float*)d_in[9];
    const float* b1  = (const float*)d_in[10];
    const float* W2  = (const float*)d_in[11];
    const float* b2  = (const float*)d_in[12];
    const float* g1  = (const float*)d_in[13];
    const float* be1 = (const float*)d_in[14];
    const float* g2  = (const float*)d_in[15];
    const float* be2 = (const float*)d_in[16];
    float* outp = (float*)d_out;   // OUTPUT IS F32 (r8 evidence)

    const size_t NEL = (size_t)MTOT * DIM;           // 16,777,216 elements
    char* wsb = (char*)d_ws;
    // Workspace guard (110,104,576 B — proven available in r6/r8).
    const size_t SMALL_FLOATS = 263168 + 2097152;    // through w2part end
    const size_t REQ = 3 * NEL * 2 + SMALL_FLOATS * 4;
    if (ws_size < REQ) return;

    bf16u* xs_bf = (bf16u*)wsb;                       // region0
    bf16u* q_bf  = (bf16u*)(wsb + NEL * 2);           // region1
    bf16u* v_bf  = (bf16u*)(wsb + 2 * NEL * 2);       // region2
    float* small = (float*)(wsb + 3 * NEL * 2);
    float* K1f      = small;                          // 65536
    float* attn2f   = small + 65536;                  // 65536
    float* w2f      = small + 131072;                 // 65536
    float* colmax   = small + 196608;                 // 1024
    float* cmaxpart = small + 197632;                 // 32768
    float* psumpart = small + 230400;                 // 32768
    float* w2part   = small + 263168;                 // 2,097,152
    // lifetime-disjoint aliases:
    bf16u* scores_bf = (bf16u*)d_out;  // live k_scores..k_out (NEL bf16 = half of d_out's f32 span)
    bf16u* oa_bf     = q_bf;           // q dead after k_scores
    bf16u* ffnin_bf  = v_bf;           // v dead after k_w2
    bf16u* h_bf      = xs_bf;          // spans region0+1; xs,oa dead after LN1
    bf16u* f2_bf     = (bf16u*)d_out;  // scores dead after k_out
    bf16u* fo_bf     = xs_bf;          // h dead after FFN2

    dim3 tb(32, 8);
    k_transpose_in<<<dim3(NN / 32, DIM / 32, NB), tb, 0, stream>>>(x, xs_bf);
    k_proj_small<<<NB * KK, 256, 0, stream>>>(C, Wq, bq, K1f);
    k_attn2<<<BH, 256, 0, stream>>>(K1f, attn2f);
    gemm_bf<0><<<dim3(MTOT / 64, DIM / 64), 256, 0, stream>>>(xs_bf, Wk, bk, nullptr, q_bf, MTOT, DIM, DIM);
    gemm_bf<0><<<dim3(MTOT / 64, DIM / 64), 256, 0, stream>>>(xs_bf, Wv, bv, nullptr, v_bf, MTOT, DIM, DIM);
    k_scores<<<dim3(BH, NN / 128), 256, 0, stream>>>(q_bf, K1f, scores_bf);
    k_cmax<<<dim3(BH, 32), 256, 0, stream>>>(scores_bf, cmaxpart);
    k_colmax<<<BH, 64, 0, stream>>>(cmaxpart, colmax);
    k_w2<<<dim3(BH, 32), 256, 0, stream>>>(scores_bf, v_bf, colmax, w2part, psumpart);
    k_w2fin<<<BH, 256, 0, stream>>>(w2part, psumpart, w2f);
    k_out<<<dim3(BH, NN / 128), 256, 0, stream>>>(scores_bf, attn2f, w2f, oa_bf);
    k_ln1<<<MTOT / 4, 256, 0, stream>>>(oa_bf, xs_bf, g1, be1, ffnin_bf);
    gemm_bf<1><<<dim3(MTOT / 64, FF / 64), 256, 0, stream>>>(ffnin_bf, W1, b1, nullptr, h_bf, MTOT, DIM, FF);
    gemm_bf<2><<<dim3(MTOT / 64, DIM / 64), 256, 0, stream>>>(h_bf, W2, b2, ffnin_bf, f2_bf, MTOT, FF, DIM);
    k_ln2<<<MTOT / 4, 256, 0, stream>>>(f2_bf, g2, be2, fo_bf);
    k_transpose_out<<<dim3(NN / 32, DIM / 32, NB), tb, 0, stream>>>(fo_bf, outp);
}

// Round 12
// 923.152 us; speedup vs baseline: 1.7740x; 1.7740x over previous
//
#include <hip/hip_runtime.h>
#include <hip/hip_bf16.h>

// ContentAgree: B=4, DIM=256, N=16384, K=64, H=4, HD=64, FF=512
// INPUTS f32, OUTPUT f32 (r8/r9 evidence). Intermediates bf16, compute f32.
// r11: fix r10's OOB — weight hi/lo buffers live at (bf16u*)d_out + NEL
// (byte-upper-half of d_out), NOT (float*)d_out + NEL (end of buffer).

#define NB 4
#define DIM 256
#define NN 16384
#define KK 64
#define HH 4
#define HD 64
#define FF 512
#define MTOT (NB * NN)           // 65536 rows
#define BH (NB * HH)             // 16

typedef unsigned short bf16u;
using bf16x8 = __attribute__((ext_vector_type(8))) __bf16;
using f32x4  = __attribute__((ext_vector_type(4))) float;

__device__ __forceinline__ float b2f(bf16u u) {
    return __uint_as_float(((unsigned)u) << 16);
}
__device__ __forceinline__ bf16u f2b(float f) {
    unsigned x = __float_as_uint(f);
    unsigned r = (x + 0x7fffu + ((x >> 16) & 1u)) >> 16;
    return (bf16u)r;
}
__device__ __forceinline__ float wave_max(float v) {
#pragma unroll
    for (int off = 32; off > 0; off >>= 1) v = fmaxf(v, __shfl_xor(v, off));
    return v;
}
__device__ __forceinline__ float wave_sum(float v) {
#pragma unroll
    for (int off = 32; off > 0; off >>= 1) v += __shfl_xor(v, off);
    return v;
}
__device__ __forceinline__ void gll16(const void* g, void* l) {
    __builtin_amdgcn_global_load_lds(
        (const __attribute__((address_space(1))) void*)g,
        (__attribute__((address_space(3))) void*)l, 16, 0, 0);
}

// ---------------------------------------------------------------- transpose in
__global__ __launch_bounds__(256) void k_transpose_in(const float* __restrict__ x,
                                                      bf16u* __restrict__ xs) {
    __shared__ float tile[32][33];
    int b = blockIdx.z;
    int n0 = blockIdx.x * 32, c0 = blockIdx.y * 32;
    int tx = threadIdx.x, ty = threadIdx.y;
#pragma unroll
    for (int i = 0; i < 32; i += 8)
        tile[ty + i][tx] = x[((size_t)b * DIM + c0 + ty + i) * NN + n0 + tx];
    __syncthreads();
#pragma unroll
    for (int i = 0; i < 32; i += 8)
        xs[((size_t)b * NN + n0 + ty + i) * DIM + c0 + tx] = f2b(tile[tx][ty + i]);
}

// ---------------------------------------------------------------- weight split
// W (K x N, f32) -> hiT/loT (N x K, bf16 hi/lo residual split)
__global__ __launch_bounds__(256) void k_wsplit(const float* __restrict__ W,
                                                bf16u* __restrict__ hiT,
                                                bf16u* __restrict__ loT,
                                                int K, int N) {
    int i = blockIdx.x * 256 + threadIdx.x;
    int k = i / N, n = i % N;
    float f = W[i];
    bf16u h = f2b(f);
    bf16u lo = f2b(f - b2f(h));
    hiT[(size_t)n * K + k] = h;
    loT[(size_t)n * K + k] = lo;
}

// ---------------------------------------------------------------- K1 = C@Wq+bq
__global__ __launch_bounds__(256) void k_proj_small(const float* __restrict__ C,
                                                    const float* __restrict__ Wq,
                                                    const float* __restrict__ bq,
                                                    float* __restrict__ K1f) {
    __shared__ float crow[DIM];
    int bk = blockIdx.x;
    int t = threadIdx.x;
    crow[t] = C[(size_t)bk * DIM + t];
    __syncthreads();
    float acc = bq[t];
    for (int d = 0; d < DIM; ++d) acc += crow[d] * Wq[d * DIM + t];
    K1f[(size_t)bk * DIM + t] = acc;
}

// ---------------------------------------------------------------- attn2
__global__ __launch_bounds__(256) void k_attn2(const float* __restrict__ K1f,
                                               float* __restrict__ attn2f) {
    __shared__ float k1s[64][65];
    __shared__ float sbuf[64][65];
    int bh = blockIdx.x;
    int b = bh >> 2, h = bh & 3;
    int t = threadIdx.x;
#pragma unroll
    for (int i = 0; i < 16; ++i) {
        int idx = t + i * 256;
        int k = idx >> 6, hd = idx & 63;
        k1s[k][hd] = K1f[((size_t)b * KK + k) * DIM + h * HD + hd];
    }
    __syncthreads();
    int k = t >> 2, j0 = (t & 3) * 16;
    for (int jj = 0; jj < 16; ++jj) {
        int j = j0 + jj;
        float acc = 0.f;
#pragma unroll
        for (int d = 0; d < 64; ++d) acc += k1s[k][d] * k1s[j][d];
        sbuf[k][j] = acc * 0.125f;
    }
    __syncthreads();
    int lane = t & 63, w = t >> 6;
    for (int r = w; r < 64; r += 4) {
        float v = sbuf[r][lane];
        float m = wave_max(v);
        float p = expf(v - m);
        float s = wave_sum(p);
        attn2f[((size_t)bh * KK + r) * KK + lane] = p / s;
    }
}

// ---------------------------------------------------------------- MFMA GEMM
// C(M,Nc) = A(M,Kd)[bf16] @ (BhT+BlT)^T + bias ; EPI: 0 none, 1 gelu, 2 +Res
// 128x128 tile, 4 waves (2x2 of 64x64), BK=32, mfma_f32_16x16x32_bf16.
// LDS layout [kb][row][8]; operands swapped => lane's f32x4 = 4 consecutive cols.
template <int EPI>
__global__ __launch_bounds__(256) void gemm_mfma(const bf16u* __restrict__ A,
                                                 const bf16u* __restrict__ BhT,
                                                 const bf16u* __restrict__ BlT,
                                                 const float* __restrict__ bias,
                                                 const bf16u* __restrict__ Res,
                                                 bf16u* __restrict__ Cout,
                                                 int Kd, int Nc) {
    __shared__ __align__(16) unsigned short ldsA[4096];
    __shared__ __align__(16) unsigned short ldsBH[4096];
    __shared__ __align__(16) unsigned short ldsBL[4096];
    int t = threadIdx.x;
    int lane = t & 63, wid = t >> 6;
    int wm = (wid & 1) * 64, wn = (wid >> 1) * 64;
    int lm = lane & 15, lk = lane >> 4;
    int m0 = blockIdx.x * 128, n0 = blockIdx.y * 128;
    f32x4 acc[4][4] = {};

    int s0 = t, s1 = t + 256;
    int am0 = m0 + (s0 & 127), ak0 = (s0 >> 7) * 8;
    int am1 = m0 + (s1 & 127), ak1 = (s1 >> 7) * 8;
    int bn0 = n0 + (s0 & 127);
    int bn1 = n0 + (s1 & 127);

    for (int k0 = 0; k0 < Kd; k0 += 32) {
        gll16(A   + (size_t)am0 * Kd + k0 + ak0, ldsA  + s0 * 8);
        gll16(A   + (size_t)am1 * Kd + k0 + ak1, ldsA  + s1 * 8);
        gll16(BhT + (size_t)bn0 * Kd + k0 + ak0, ldsBH + s0 * 8);
        gll16(BhT + (size_t)bn1 * Kd + k0 + ak1, ldsBH + s1 * 8);
        gll16(BlT + (size_t)bn0 * Kd + k0 + ak0, ldsBL + s0 * 8);
        gll16(BlT + (size_t)bn1 * Kd + k0 + ak1, ldsBL + s1 * 8);
        __syncthreads();
        const bf16x8* pa = reinterpret_cast<const bf16x8*>(ldsA);
        const bf16x8* ph = reinterpret_cast<const bf16x8*>(ldsBH);
        const bf16x8* pl = reinterpret_cast<const bf16x8*>(ldsBL);
        bf16x8 aF[4], hF[4], lF[4];
#pragma unroll
        for (int i = 0; i < 4; ++i) {
            aF[i] = pa[lk * 128 + wm + i * 16 + lm];
            hF[i] = ph[lk * 128 + wn + i * 16 + lm];
            lF[i] = pl[lk * 128 + wn + i * 16 + lm];
        }
#pragma unroll
        for (int mi = 0; mi < 4; ++mi)
#pragma unroll
            for (int ni = 0; ni < 4; ++ni) {
                acc[mi][ni] = __builtin_amdgcn_mfma_f32_16x16x32_bf16(hF[ni], aF[mi], acc[mi][ni], 0, 0, 0);
                acc[mi][ni] = __builtin_amdgcn_mfma_f32_16x16x32_bf16(lF[ni], aF[mi], acc[mi][ni], 0, 0, 0);
            }
        __syncthreads();
    }
#pragma unroll
    for (int mi = 0; mi < 4; ++mi) {
        int mg = m0 + wm + mi * 16 + lm;
#pragma unroll
        for (int ni = 0; ni < 4; ++ni) {
            int ng = n0 + wn + ni * 16 + lk * 4;
            float4 bs = *reinterpret_cast<const float4*>(bias + ng);
            float v[4] = {acc[mi][ni][0] + bs.x, acc[mi][ni][1] + bs.y,
                          acc[mi][ni][2] + bs.z, acc[mi][ni][3] + bs.w};
            if (EPI == 1) {
#pragma unroll
                for (int j = 0; j < 4; ++j)
                    v[j] = 0.5f * v[j] * (1.0f + erff(v[j] * 0.7071067811865476f));
            }
            if (EPI == 2) {
                ushort4 r = *reinterpret_cast<const ushort4*>(Res + (size_t)mg * Nc + ng);
                v[0] += b2f(r.x); v[1] += b2f(r.y); v[2] += b2f(r.z); v[3] += b2f(r.w);
            }
            ushort4 o = {f2b(v[0]), f2b(v[1]), f2b(v[2]), f2b(v[3])};
            *reinterpret_cast<ushort4*>(Cout + (size_t)mg * Nc + ng) = o;
        }
    }
}

// ---------------------------------------------------------------- scores
__global__ __launch_bounds__(256) void k_scores(const bf16u* __restrict__ Qbuf,
                                                const float* __restrict__ K1f,
                                                bf16u* __restrict__ scores) {
    __shared__ float k1t[64][65];
    __shared__ float qrow[4][64];
    int bh = blockIdx.x;
    int b = bh >> 2, h = bh & 3;
    int n0 = blockIdx.y * 128;
    int t = threadIdx.x;
#pragma unroll
    for (int i = 0; i < 16; ++i) {
        int idx = t + i * 256;
        int k = idx >> 6, hd = idx & 63;
        k1t[hd][k] = K1f[((size_t)b * KK + k) * DIM + h * HD + hd];
    }
    __syncthreads();
    int w = t >> 6, lane = t & 63;
    for (int it = 0; it < 32; ++it) {
        int n = n0 + it * 4 + w;
        qrow[w][lane] = b2f(Qbuf[((size_t)b * NN + n) * DIM + h * HD + lane]);
        __syncthreads();
        float acc = 0.f;
#pragma unroll
        for (int d = 0; d < 64; ++d) acc += qrow[w][d] * k1t[d][lane];
        scores[((size_t)bh * NN + n) * KK + lane] = f2b(acc * 0.125f);
        __syncthreads();
    }
}

// ---------------------------------------------------------------- col max (chunked)
__global__ __launch_bounds__(256) void k_cmax(const bf16u* __restrict__ scores,
                                              float* __restrict__ cmaxpart) {
    int bh = blockIdx.x, ch = blockIdx.y;
    int t = threadIdx.x, w = t >> 6, lane = t & 63;
    int n0 = ch * 512;
    float m = -1e30f;
    for (int i = 0; i < 128; ++i) {
        int n = n0 + i * 4 + w;
        m = fmaxf(m, b2f(scores[((size_t)bh * NN + n) * KK + lane]));
    }
    __shared__ float red[4][64];
    red[w][lane] = m;
    __syncthreads();
    if (w == 0) {
        m = fmaxf(fmaxf(red[0][lane], red[1][lane]), fmaxf(red[2][lane], red[3][lane]));
        cmaxpart[((size_t)bh * 32 + ch) * 64 + lane] = m;
    }
}

__global__ void k_colmax(const float* __restrict__ cmaxpart, float* __restrict__ colmax) {
    int bh = blockIdx.x, lane = threadIdx.x;
    float m = -1e30f;
    for (int ch = 0; ch < 32; ++ch)
        m = fmaxf(m, cmaxpart[((size_t)bh * 32 + ch) * 64 + lane]);
    colmax[bh * 64 + lane] = m;
}

// ---------------------------------------------------------------- w2 partials
__global__ __launch_bounds__(256) void k_w2(const bf16u* __restrict__ scores,
                                            const bf16u* __restrict__ Vbuf,
                                            const float* __restrict__ colmax,
                                            float* __restrict__ w2part,
                                            float* __restrict__ psumpart) {
    int bh = blockIdx.x, ch = blockIdx.y;
    int b = bh >> 2, h = bh & 3;
    int t = threadIdx.x, w = t >> 6, lane = t & 63;
    float mk = colmax[bh * 64 + lane];
    float acc[16] = {};
    float psum = 0.f;
    __shared__ float prow[4][64], vrow[4][64];
    int n0 = ch * 512;
    for (int i = 0; i < 128; ++i) {
        int n = n0 + i * 4 + w;
        float p = expf(b2f(scores[((size_t)bh * NN + n) * KK + lane]) - mk);
        psum += p;
        prow[w][lane] = p;
        vrow[w][lane] = b2f(Vbuf[((size_t)b * NN + n) * DIM + h * HD + lane]);
        __syncthreads();
#pragma unroll
        for (int r = 0; r < 4; ++r) {
            float v = vrow[r][lane];
#pragma unroll
            for (int j = 0; j < 16; ++j) acc[j] += prow[r][w + 4 * j] * v;
        }
        __syncthreads();
    }
#pragma unroll
    for (int j = 0; j < 16; ++j) {
        int k = w + 4 * j;
        w2part[(((size_t)bh * 32 + ch) * 64 + k) * 64 + lane] = acc[j];
    }
    __shared__ float pred[4][64];
    pred[w][lane] = psum;
    __syncthreads();
    if (t < 64) {
        float s = pred[0][t] + pred[1][t] + pred[2][t] + pred[3][t];
        psumpart[((size_t)bh * 32 + ch) * 64 + t] = s;
    }
}

__global__ __launch_bounds__(256) void k_w2fin(const float* __restrict__ w2part,
                                               const float* __restrict__ psumpart,
                                               float* __restrict__ w2f) {
    int bh = blockIdx.x, t = threadIdx.x;
    __shared__ float stot[64];
    if (t < 64) {
        float s = 0.f;
        for (int ch = 0; ch < 32; ++ch) s += psumpart[((size_t)bh * 32 + ch) * 64 + t];
        stot[t] = s;
    }
    __syncthreads();
#pragma unroll
    for (int i = 0; i < 16; ++i) {
        int idx = t + i * 256;
        int k = idx >> 6, hd = idx & 63;
        float s = 0.f;
        for (int ch = 0; ch < 32; ++ch)
            s += w2part[(((size_t)bh * 32 + ch) * 64 + k) * 64 + hd];
        w2f[(size_t)bh * 4096 + idx] = s / stot[k];
    }
}

// ---------------------------------------------------------------- fused row out
__global__ __launch_bounds__(256) void k_out(const bf16u* __restrict__ scores,
                                             const float* __restrict__ attn2f,
                                             const float* __restrict__ w2f,
                                             bf16u* __restrict__ out_attn) {
    __shared__ float a2[64][65];
    __shared__ float w2[64][65];
    __shared__ float arow[4][64];
    __shared__ float w1row[4][64];
    int bh = blockIdx.x;
    int b = bh >> 2, h = bh & 3;
    int n0 = blockIdx.y * 128;
    int t = threadIdx.x, w = t >> 6, lane = t & 63;
#pragma unroll
    for (int i = 0; i < 16; ++i) {
        int idx = t + i * 256;
        int k = idx >> 6, j = idx & 63;
        a2[k][j] = attn2f[(size_t)bh * 4096 + idx];
        w2[k][j] = w2f[(size_t)bh * 4096 + idx];
    }
    __syncthreads();
    for (int it = 0; it < 32; ++it) {
        int n = n0 + it * 4 + w;
        float s = b2f(scores[((size_t)bh * NN + n) * KK + lane]);
        float m = wave_max(s);
        float p = expf(s - m);
        float sum = wave_sum(p);
        arow[w][lane] = p / sum;
        __syncthreads();
        float acc = 0.f;
#pragma unroll
        for (int k = 0; k < 64; ++k) acc += arow[w][k] * a2[k][lane];
        w1row[w][lane] = acc;
        __syncthreads();
        float o = 0.f;
#pragma unroll
        for (int k = 0; k < 64; ++k) o += w1row[w][k] * w2[k][lane];
        out_attn[((size_t)b * NN + n) * DIM + lane * 4 + h] = f2b(o);
        __syncthreads();
    }
}

// ---------------------------------------------------------------- LN kernels
__global__ __launch_bounds__(256) void k_ln1(const bf16u* __restrict__ oa,
                                             const bf16u* __restrict__ xs,
                                             const float* __restrict__ g,
                                             const float* __restrict__ bb,
                                             bf16u* __restrict__ ffn_in) {
    int m = blockIdx.x * 4 + (threadIdx.x >> 6);
    int lane = threadIdx.x & 63;
    ushort4 a = reinterpret_cast<const ushort4*>(oa + (size_t)m * DIM)[lane];
    ushort4 x = reinterpret_cast<const ushort4*>(xs + (size_t)m * DIM)[lane];
    float v[4] = {b2f(a.x) + b2f(x.x), b2f(a.y) + b2f(x.y),
                  b2f(a.z) + b2f(x.z), b2f(a.w) + b2f(x.w)};
    float s = wave_sum(v[0] + v[1] + v[2] + v[3]);
    float mean = s * (1.0f / 256.0f);
    float q = 0.f;
#pragma unroll
    for (int i = 0; i < 4; ++i) { float d = v[i] - mean; q += d * d; }
    q = wave_sum(q);
    float inv = rsqrtf(q * (1.0f / 256.0f) + 1e-5f);
    ushort4 o;
    bf16u* po = &o.x;
#pragma unroll
    for (int i = 0; i < 4; ++i) {
        int c = lane * 4 + i;
        po[i] = f2b((v[i] - mean) * inv * g[c] + bb[c]);
    }
    reinterpret_cast<ushort4*>(ffn_in + (size_t)m * DIM)[lane] = o;
}

__global__ __launch_bounds__(256) void k_ln2(const bf16u* __restrict__ f2,
                                             const float* __restrict__ g,
                                             const float* __restrict__ bb,
                                             bf16u* __restrict__ fo) {
    int m = blockIdx.x * 4 + (threadIdx.x >> 6);
    int lane = threadIdx.x & 63;
    ushort4 a = reinterpret_cast<const ushort4*>(f2 + (size_t)m * DIM)[lane];
    float v[4] = {b2f(a.x), b2f(a.y), b2f(a.z), b2f(a.w)};
    float s = wave_sum(v[0] + v[1] + v[2] + v[3]);
    float mean = s * (1.0f / 256.0f);
    float q = 0.f;
#pragma unroll
    for (int i = 0; i < 4; ++i) { float d = v[i] - mean; q += d * d; }
    q = wave_sum(q);
    float inv = rsqrtf(q * (1.0f / 256.0f) + 1e-5f);
    ushort4 o;
    bf16u* po = &o.x;
#pragma unroll
    for (int i = 0; i < 4; ++i) {
        int c = lane * 4 + i;
        po[i] = f2b((v[i] - mean) * inv * g[c] + bb[c]);
    }
    reinterpret_cast<ushort4*>(fo + (size_t)m * DIM)[lane] = o;
}

// ---------------------------------------------------------------- transpose out
__global__ __launch_bounds__(256) void k_transpose_out(const bf16u* __restrict__ fo,
                                                       float* __restrict__ out) {
    __shared__ bf16u tile[32][34];
    int b = blockIdx.z;
    int n0 = blockIdx.x * 32, c0 = blockIdx.y * 32;
    int tx = threadIdx.x, ty = threadIdx.y;
#pragma unroll
    for (int i = 0; i < 32; i += 8)
        tile[ty + i][tx] = fo[((size_t)b * NN + n0 + ty + i) * DIM + c0 + tx];
    __syncthreads();
#pragma unroll
    for (int i = 0; i < 32; i += 8)
        out[((size_t)b * DIM + c0 + ty + i) * NN + n0 + tx] = b2f(tile[tx][ty + i]);
}

// ---------------------------------------------------------------- launch
extern "C" void kernel_launch(void* const* d_in, const int* in_sizes, int n_in,
                              void* d_out, int out_size, void* d_ws, size_t ws_size,
                              hipStream_t stream) {
    const float* x   = (const float*)d_in[0];
    const float* C   = (const float*)d_in[1];
    const float* Wq  = (const float*)d_in[3];
    const float* bq  = (const float*)d_in[4];
    const float* Wk  = (const float*)d_in[5];
    const float* bk  = (const float*)d_in[6];
    const float* Wv  = (const float*)d_in[7];
    const float* bv  = (const float*)d_in[8];
    const float* W1  = (const float*)d_in[9];
    const float* b1  = (const float*)d_in[10];
    const float* W2  = (const float*)d_in[11];
    const float* b2  = (const float*)d_in[12];
    const float* g1  = (const float*)d_in[13];
    const float* be1 = (const float*)d_in[14];
    const float* g2  = (const float*)d_in[15];
    const float* be2 = (const float*)d_in[16];
    float* outp = (float*)d_out;

    const size_t NEL = (size_t)MTOT * DIM;           // 16,777,216 elements
    char* wsb = (char*)d_ws;
    const size_t SMALL_FLOATS = 263168 + 2097152;
    const size_t REQ = 3 * NEL * 2 + SMALL_FLOATS * 4;
    if (ws_size < REQ) return;

    bf16u* xs_bf = (bf16u*)wsb;                       // region0
    bf16u* q_bf  = (bf16u*)(wsb + NEL * 2);           // region1
    bf16u* v_bf  = (bf16u*)(wsb + 2 * NEL * 2);       // region2
    float* small = (float*)(wsb + 3 * NEL * 2);
    float* K1f      = small;
    float* attn2f   = small + 65536;
    float* w2f      = small + 131072;
    float* colmax   = small + 196608;
    float* cmaxpart = small + 197632;
    float* psumpart = small + 230400;
    float* w2part   = small + 263168;
    // lifetime-disjoint aliases:
    bf16u* scores_bf = (bf16u*)d_out;  // bf16 [0, NEL) = lower byte-half of d_out
    bf16u* oa_bf     = q_bf;
    bf16u* ffnin_bf  = v_bf;
    bf16u* h_bf      = xs_bf;          // region0+1 after LN1
    bf16u* f2_bf     = (bf16u*)d_out;
    bf16u* fo_bf     = xs_bf;
    // weight hi/lo transposed buffers: UPPER BYTE-HALF of d_out,
    // i.e. bf16 elements [NEL, NEL+786432) — inside the NEL*4-byte buffer.
    // (r10 bug: "(float*)d_out + NEL" pointed at the END of d_out -> OOB fault.)
    bf16u* wt = (bf16u*)d_out + NEL;
    bf16u *WkT_h = wt,            *WkT_l = wt + 65536;
    bf16u *WvT_h = wt + 131072,   *WvT_l = wt + 196608;
    bf16u *W1T_h = wt + 262144,   *W1T_l = wt + 393216;
    bf16u *W2T_h = wt + 524288,   *W2T_l = wt + 655360;

    dim3 tb(32, 8);
    k_transpose_in<<<dim3(NN / 32, DIM / 32, NB), tb, 0, stream>>>(x, xs_bf);
    k_wsplit<<<256, 256, 0, stream>>>(Wk, WkT_h, WkT_l, DIM, DIM);
    k_wsplit<<<256, 256, 0, stream>>>(Wv, WvT_h, WvT_l, DIM, DIM);
    k_wsplit<<<512, 256, 0, stream>>>(W1, W1T_h, W1T_l, DIM, FF);
    k_wsplit<<<512, 256, 0, stream>>>(W2, W2T_h, W2T_l, FF, DIM);
    k_proj_small<<<NB * KK, 256, 0, stream>>>(C, Wq, bq, K1f);
    k_attn2<<<BH, 256, 0, stream>>>(K1f, attn2f);
    gemm_mfma<0><<<dim3(MTOT / 128, DIM / 128), 256, 0, stream>>>(xs_bf, WkT_h, WkT_l, bk, nullptr, q_bf, DIM, DIM);
    gemm_mfma<0><<<dim3(MTOT / 128, DIM / 128), 256, 0, stream>>>(xs_bf, WvT_h, WvT_l, bv, nullptr, v_bf, DIM, DIM);
    k_scores<<<dim3(BH, NN / 128), 256, 0, stream>>>(q_bf, K1f, scores_bf);
    k_cmax<<<dim3(BH, 32), 256, 0, stream>>>(scores_bf, cmaxpart);
    k_colmax<<<BH, 64, 0, stream>>>(cmaxpart, colmax);
    k_w2<<<dim3(BH, 32), 256, 0, stream>>>(scores_bf, v_bf, colmax, w2part, psumpart);
    k_w2fin<<<BH, 256, 0, stream>>>(w2part, psumpart, w2f);
    k_out<<<dim3(BH, NN / 128), 256, 0, stream>>>(scores_bf, attn2f, w2f, oa_bf);
    k_ln1<<<MTOT / 4, 256, 0, stream>>>(oa_bf, xs_bf, g1, be1, ffnin_bf);
    gemm_mfma<1><<<dim3(MTOT / 128, FF / 128), 256, 0, stream>>>(ffnin_bf, W1T_h, W1T_l, b1, nullptr, h_bf, DIM, FF);
    gemm_mfma<2><<<dim3(MTOT / 128, DIM / 128), 256, 0, stream>>>(h_bf, W2T_h, W2T_l, b2, ffnin_bf, f2_bf, FF, DIM);
    k_ln2<<<MTOT / 4, 256, 0, stream>>>(f2_bf, g2, be2, fo_bf);
    k_transpose_out<<<dim3(NN / 32, DIM / 32, NB), tb, 0, stream>>>(fo_bf, outp);
}